// Round 1
// baseline (2787.061 us; speedup 1.0000x reference)
//
#include <hip/hip_runtime.h>
#include <math.h>

#define NRAYS 8192
#define NSAMP 256
#define GD    160
#define CF    12
#define HID   128
#define INDIM 39   // CF + 3 + 3*2*4

static constexpr float ACT_SHIFT = -13.815509557963774f;  // log(1/(1-1e-6)-1), fp64-derived
static constexpr float EPSF      = 1e-10f;

__global__ __launch_bounds__(256, 1)
void dvgo_fused(const float* __restrict__ ray_pts,
                const float* __restrict__ viewdirs,
                const float* __restrict__ density_grid,
                const float* __restrict__ k0,
                const float* __restrict__ w0,
                const float* __restrict__ b0,
                const float* __restrict__ w1,
                const float* __restrict__ b1,
                const float* __restrict__ w2,
                const float* __restrict__ b2,
                float* __restrict__ out)
{
    __shared__ __align__(16) float s_w0[INDIM * HID];   // 19968 B
    __shared__ __align__(16) float s_w1[HID * HID];     // 65536 B
    __shared__ __align__(16) float s_w2[HID * 3];       // 1536 B
    __shared__ __align__(16) float s_l0b[HID];          // per-ray folded layer0 bias
    __shared__ __align__(16) float s_b1[HID];
    __shared__ float s_vemb[27];
    __shared__ float s_scan[NSAMP];
    __shared__ float s_red[12];

    const int ray = blockIdx.x;
    const int t   = threadIdx.x;

    // ---- cooperative weight staging (global -> LDS), coalesced float4 ----
    {
        const float4* s4 = (const float4*)w0;
        float4*       d4 = (float4*)s_w0;
        for (int i = t; i < INDIM*HID/4; i += 256) d4[i] = s4[i];
        s4 = (const float4*)w1; d4 = (float4*)s_w1;
        for (int i = t; i < HID*HID/4; i += 256) d4[i] = s4[i];
        s4 = (const float4*)w2; d4 = (float4*)s_w2;
        for (int i = t; i < HID*3/4; i += 256) d4[i] = s4[i];
        if (t < HID) s_b1[t] = b1[t];
    }

    // ---- per-ray view embedding (27 values), computed once ----
    if (t == 0) {
        float vx = viewdirs[ray*3+0], vy = viewdirs[ray*3+1], vz = viewdirs[ray*3+2];
        float inv = 1.0f / (sqrtf(vx*vx + vy*vy + vz*vz) + EPSF);
        float dv[3] = { vx*inv, vy*inv, vz*inv };
        s_vemb[0] = dv[0]; s_vemb[1] = dv[1]; s_vemb[2] = dv[2];
        #pragma unroll
        for (int i = 0; i < 3; ++i) {
            #pragma unroll
            for (int f = 0; f < 4; ++f) {
                float ang = dv[i] * (float)(1 << f);
                s_vemb[3  + i*4 + f] = sinf(ang);
                s_vemb[15 + i*4 + f] = cosf(ang);
            }
        }
    }
    __syncthreads();

    // ---- fold ray-uniform vemb contribution into layer0 bias ----
    if (t < HID) {
        float acc = b0[t];
        #pragma unroll
        for (int k = 0; k < 27; ++k)
            acc = fmaf(s_vemb[k], s_w0[(CF + k)*HID + t], acc);
        s_l0b[t] = acc;
    }

    // ---- per-sample trilinear gather (density + 12-ch feat) ----
    float px = ray_pts[(ray*NSAMP + t)*3 + 0];
    float py = ray_pts[(ray*NSAMP + t)*3 + 1];
    float pz = ray_pts[(ray*NSAMP + t)*3 + 2];
    px = fminf(fmaxf(px, 0.f), 1.f) * (float)(GD-1);
    py = fminf(fmaxf(py, 0.f), 1.f) * (float)(GD-1);
    pz = fminf(fmaxf(pz, 0.f), 1.f) * (float)(GD-1);
    int ix = min((int)px, GD-2);   // px >= 0 -> trunc == floor
    int iy = min((int)py, GD-2);
    int iz = min((int)pz, GD-2);
    float fx = px - (float)ix, fy = py - (float)iy, fz = pz - (float)iz;
    float wx[2] = {1.f - fx, fx}, wy[2] = {1.f - fy, fy}, wz[2] = {1.f - fz, fz};
    int base = (ix*GD + iy)*GD + iz;

    float dens = 0.f;
    float feat[CF];
    #pragma unroll
    for (int c = 0; c < CF; ++c) feat[c] = 0.f;

    #pragma unroll
    for (int dx = 0; dx < 2; ++dx)
    #pragma unroll
    for (int dy = 0; dy < 2; ++dy)
    #pragma unroll
    for (int dz = 0; dz < 2; ++dz) {
        int idx = base + dx*(GD*GD) + dy*GD + dz;
        float wc = wx[dx]*wy[dy]*wz[dz];
        dens = fmaf(density_grid[idx], wc, dens);
        const float4* kp = (const float4*)(k0 + (long)idx*CF);  // 48B-aligned
        float4 a = kp[0], b = kp[1], c = kp[2];
        feat[0]  = fmaf(a.x, wc, feat[0]);  feat[1]  = fmaf(a.y, wc, feat[1]);
        feat[2]  = fmaf(a.z, wc, feat[2]);  feat[3]  = fmaf(a.w, wc, feat[3]);
        feat[4]  = fmaf(b.x, wc, feat[4]);  feat[5]  = fmaf(b.y, wc, feat[5]);
        feat[6]  = fmaf(b.z, wc, feat[6]);  feat[7]  = fmaf(b.w, wc, feat[7]);
        feat[8]  = fmaf(c.x, wc, feat[8]);  feat[9]  = fmaf(c.y, wc, feat[9]);
        feat[10] = fmaf(c.z, wc, feat[10]); feat[11] = fmaf(c.w, wc, feat[11]);
    }

    // ---- alpha + block-wide product scan (cumprod over samples) ----
    float sv    = dens + ACT_SHIFT;
    float rs    = rsqrtf(1.0f + expf(sv));   // (1+e^s)^(-1/2)
    float alpha = 1.0f - rs;
    float one_m = rs + EPSF;                 // 1 - alpha + EPS

    s_scan[t] = one_m;
    __syncthreads();                         // also covers s_l0b / weight staging
    float x = one_m;
    #pragma unroll
    for (int off = 1; off < NSAMP; off <<= 1) {
        float prev = (t >= off) ? s_scan[t - off] : 1.0f;
        __syncthreads();
        x *= prev;
        s_scan[t] = x;
        __syncthreads();
    }
    float T_excl        = (t == 0) ? 1.0f : s_scan[t - 1];
    float wgt_s         = alpha * T_excl;
    float alphainv_last = s_scan[NSAMP - 1];

    // ---- layer 0: 12 x 128 (vemb part pre-folded into s_l0b) ----
    float h[HID];
    #pragma unroll
    for (int jc = 0; jc < HID; jc += 4) {
        const float4 bb = *(const float4*)&s_l0b[jc];
        float a0 = bb.x, a1 = bb.y, a2 = bb.z, a3 = bb.w;
        #pragma unroll
        for (int k = 0; k < CF; ++k) {
            float4 wv = *(const float4*)&s_w0[k*HID + jc];
            a0 = fmaf(feat[k], wv.x, a0);
            a1 = fmaf(feat[k], wv.y, a1);
            a2 = fmaf(feat[k], wv.z, a2);
            a3 = fmaf(feat[k], wv.w, a3);
        }
        h[jc+0] = fmaxf(a0, 0.f); h[jc+1] = fmaxf(a1, 0.f);
        h[jc+2] = fmaxf(a2, 0.f); h[jc+3] = fmaxf(a3, 0.f);
    }

    // ---- layer 1 (128x128) fused with layer 2 (128x3) ----
    float r0 = b2[0], r1 = b2[1], r2 = b2[2];
    for (int jc = 0; jc < HID; jc += 4) {   // rolled: only LDS dynamic indexing
        const float4 bb = *(const float4*)&s_b1[jc];
        float a0 = bb.x, a1 = bb.y, a2 = bb.z, a3 = bb.w;
        #pragma unroll
        for (int k = 0; k < HID; ++k) {     // h[k] register-indexed -> full unroll
            float4 wv = *(const float4*)&s_w1[k*HID + jc];
            a0 = fmaf(h[k], wv.x, a0);
            a1 = fmaf(h[k], wv.y, a1);
            a2 = fmaf(h[k], wv.z, a2);
            a3 = fmaf(h[k], wv.w, a3);
        }
        a0 = fmaxf(a0, 0.f); a1 = fmaxf(a1, 0.f);
        a2 = fmaxf(a2, 0.f); a3 = fmaxf(a3, 0.f);
        r0 = fmaf(a0, s_w2[(jc+0)*3+0], r0);
        r1 = fmaf(a0, s_w2[(jc+0)*3+1], r1);
        r2 = fmaf(a0, s_w2[(jc+0)*3+2], r2);
        r0 = fmaf(a1, s_w2[(jc+1)*3+0], r0);
        r1 = fmaf(a1, s_w2[(jc+1)*3+1], r1);
        r2 = fmaf(a1, s_w2[(jc+1)*3+2], r2);
        r0 = fmaf(a2, s_w2[(jc+2)*3+0], r0);
        r1 = fmaf(a2, s_w2[(jc+2)*3+1], r1);
        r2 = fmaf(a2, s_w2[(jc+2)*3+2], r2);
        r0 = fmaf(a3, s_w2[(jc+3)*3+0], r0);
        r1 = fmaf(a3, s_w2[(jc+3)*3+1], r1);
        r2 = fmaf(a3, s_w2[(jc+3)*3+2], r2);
    }

    // ---- sigmoid, weight, block-reduce, write ----
    float c0 = wgt_s / (1.0f + expf(-r0));
    float c1 = wgt_s / (1.0f + expf(-r1));
    float c2 = wgt_s / (1.0f + expf(-r2));

    #pragma unroll
    for (int off = 32; off > 0; off >>= 1) {
        c0 += __shfl_down(c0, off);
        c1 += __shfl_down(c1, off);
        c2 += __shfl_down(c2, off);
    }
    if ((t & 63) == 0) {
        int wv = t >> 6;
        s_red[wv*3+0] = c0; s_red[wv*3+1] = c1; s_red[wv*3+2] = c2;
    }
    __syncthreads();
    if (t == 0) {
        out[ray*3+0] = s_red[0] + s_red[3] + s_red[6] + s_red[9]  + alphainv_last;
        out[ray*3+1] = s_red[1] + s_red[4] + s_red[7] + s_red[10] + alphainv_last;
        out[ray*3+2] = s_red[2] + s_red[5] + s_red[8] + s_red[11] + alphainv_last;
    }
}

extern "C" void kernel_launch(void* const* d_in, const int* in_sizes, int n_in,
                              void* d_out, int out_size, void* d_ws, size_t ws_size,
                              hipStream_t stream) {
    const float* ray_pts      = (const float*)d_in[0];
    const float* viewdirs     = (const float*)d_in[1];
    const float* density_grid = (const float*)d_in[2];
    const float* k0           = (const float*)d_in[3];
    const float* w0           = (const float*)d_in[4];
    const float* b0           = (const float*)d_in[5];
    const float* w1           = (const float*)d_in[6];
    const float* b1           = (const float*)d_in[7];
    const float* w2           = (const float*)d_in[8];
    const float* b2           = (const float*)d_in[9];
    float*       outp         = (float*)d_out;

    dvgo_fused<<<dim3(NRAYS), dim3(256), 0, stream>>>(
        ray_pts, viewdirs, density_grid, k0, w0, b0, w1, b1, w2, b2, outp);
}

// Round 2
// 671.857 us; speedup vs baseline: 4.1483x; 4.1483x over previous
//
#include <hip/hip_runtime.h>
#include <math.h>

#define NRAYS 8192
#define NSAMP 256
#define GD    160
#define CF    12
#define HID   128
#define RPB   16           // rays per block
#define W0P   48           // s_w0a row pitch (bf16 elems), 96 B, 16B-aligned
#define W1P   152          // s_w1a row pitch (bf16 elems), 304 B -> 8 words/bank balanced

static constexpr float ACT_SHIFT = -13.815509557963774f;
static constexpr float EPSF      = 1e-10f;

typedef __attribute__((ext_vector_type(8)))  short bf16x8;
typedef __attribute__((ext_vector_type(16))) float f32x16;

union FragU { unsigned u[4]; uint4 q; bf16x8 v; };

__device__ __forceinline__ unsigned short bf16rne(float f) {
    unsigned u = __float_as_uint(f);
    return (unsigned short)((u + 0x7FFFu + ((u >> 16) & 1u)) >> 16);
}
// pack two fp32 -> bf16x2 (truncate): low half = lo, high half = hi
__device__ __forceinline__ unsigned pack2(float lo, float hi) {
    return __builtin_amdgcn_perm(__float_as_uint(hi), __float_as_uint(lo), 0x07060302u);
}
__device__ __forceinline__ bf16x8 ld_frag(const unsigned short* p) {
    FragU f; f.q = *(const uint4*)p; return f.v;
}

__global__ __launch_bounds__(256, 2)
void dvgo_mfma(const float* __restrict__ ray_pts,
               const float* __restrict__ viewdirs,
               const float* __restrict__ density_grid,
               const float* __restrict__ k0,
               const float* __restrict__ w0,
               const float* __restrict__ b0,
               const float* __restrict__ w1,
               const float* __restrict__ b1,
               const float* __restrict__ w2,
               const float* __restrict__ b2,
               float* __restrict__ out)
{
    __shared__ __align__(16) unsigned short s_w1a[HID * W1P];  // W1^T bf16: [out][in] 38.0 KB
    __shared__ __align__(16) unsigned short s_w0a[HID * W0P];  // W0^T bf16: [out][k48] 12.0 KB
    __shared__ __align__(16) float4 s_w2b[HID];                // {w2[d][0..2], b1[d]}  2 KB
    __shared__ float s_wtot[2][4];
    __shared__ float s_red[2][4][3];

    const int t    = threadIdx.x;
    const int lane = t & 63;
    const int w    = t >> 6;
    const int nidx = lane & 31;
    const int qh   = lane >> 5;   // 32-row half selector

    // ---------------- per-block weight staging (bf16, transposed) -------------
    for (int e = t; e < HID * HID; e += 256) {
        int i = e >> 7, o = e & 127;                  // w1[i][o] -> s_w1a[o][i]
        s_w1a[o * W1P + i] = bf16rne(w1[e]);
    }
    for (int e = t; e < 39 * HID; e += 256) {
        int i = e >> 7, o = e & 127;                  // w0[i][o] -> s_w0a[o][i]
        s_w0a[o * W0P + i] = bf16rne(w0[e]);
    }
    if (t < HID) {
        s_w0a[t * W0P + 39] = bf16rne(b0[t]);         // bias via ones-row (k=39)
        #pragma unroll
        for (int i = 40; i < 48; ++i) s_w0a[t * W0P + i] = 0;
        s_w2b[t] = make_float4(w2[t * 3 + 0], w2[t * 3 + 1], w2[t * 3 + 2], b1[t]);
    }
    const float b2x = b2[0], b2y = b2[1], b2z = b2[2];
    __syncthreads();

    #pragma unroll 1
    for (int j = 0; j < RPB; ++j) {
        const int ray = blockIdx.x * RPB + j;
        const int par = j & 1;

        // ---------------- trilinear gather (fp32), sample = t -----------------
        float px = ray_pts[(ray * NSAMP + t) * 3 + 0];
        float py = ray_pts[(ray * NSAMP + t) * 3 + 1];
        float pz = ray_pts[(ray * NSAMP + t) * 3 + 2];
        px = fminf(fmaxf(px, 0.f), 1.f) * (float)(GD - 1);
        py = fminf(fmaxf(py, 0.f), 1.f) * (float)(GD - 1);
        pz = fminf(fmaxf(pz, 0.f), 1.f) * (float)(GD - 1);
        int ix = min((int)px, GD - 2);
        int iy = min((int)py, GD - 2);
        int iz = min((int)pz, GD - 2);
        float fx = px - (float)ix, fy = py - (float)iy, fz = pz - (float)iz;
        float wx[2] = {1.f - fx, fx}, wy[2] = {1.f - fy, fy}, wz[2] = {1.f - fz, fz};
        int base = (ix * GD + iy) * GD + iz;

        float dens = 0.f;
        float feat[CF];
        #pragma unroll
        for (int c = 0; c < CF; ++c) feat[c] = 0.f;
        #pragma unroll
        for (int dx = 0; dx < 2; ++dx)
        #pragma unroll
        for (int dy = 0; dy < 2; ++dy)
        #pragma unroll
        for (int dz = 0; dz < 2; ++dz) {
            int idx = base + dx * (GD * GD) + dy * GD + dz;
            float wc = wx[dx] * wy[dy] * wz[dz];
            dens = fmaf(density_grid[idx], wc, dens);
            const float4* kp = (const float4*)(k0 + (long)idx * CF);
            float4 a = kp[0], b = kp[1], c = kp[2];
            feat[0]  = fmaf(a.x, wc, feat[0]);  feat[1]  = fmaf(a.y, wc, feat[1]);
            feat[2]  = fmaf(a.z, wc, feat[2]);  feat[3]  = fmaf(a.w, wc, feat[3]);
            feat[4]  = fmaf(b.x, wc, feat[4]);  feat[5]  = fmaf(b.y, wc, feat[5]);
            feat[6]  = fmaf(b.z, wc, feat[6]);  feat[7]  = fmaf(b.w, wc, feat[7]);
            feat[8]  = fmaf(c.x, wc, feat[8]);  feat[9]  = fmaf(c.y, wc, feat[9]);
            feat[10] = fmaf(c.z, wc, feat[10]); feat[11] = fmaf(c.w, wc, feat[11]);
        }

        // ---------------- alpha + product scan (shfl-based) -------------------
        float sv    = dens + ACT_SHIFT;
        float rs    = rsqrtf(1.0f + __expf(sv));
        float alpha = 1.0f - rs;
        float x     = rs + EPSF;              // 1 - alpha + EPS
        #pragma unroll
        for (int off = 1; off < 64; off <<= 1) {
            float y = __shfl_up(x, off);
            if (lane >= off) x *= y;
        }
        if (lane == 63) s_wtot[par][w] = x;
        __syncthreads();
        float t0 = s_wtot[par][0], t1 = s_wtot[par][1];
        float t2 = s_wtot[par][2], t3 = s_wtot[par][3];
        float pre = 1.f;
        if (w > 0) pre *= t0;
        if (w > 1) pre *= t1;
        if (w > 2) pre *= t2;
        const float ainv = t0 * t1 * t2 * t3;           // alphainv_last
        float ex = __shfl_up(x, 1);
        if (lane == 0) ex = 1.f;
        const float wgt = alpha * ex * pre;             // per-sample ray weight

        // ---------------- view embedding (ray-uniform, all threads) -----------
        float vx = viewdirs[ray * 3 + 0], vy = viewdirs[ray * 3 + 1], vz = viewdirs[ray * 3 + 2];
        float inv = 1.0f / (sqrtf(vx * vx + vy * vy + vz * vz) + EPSF);
        float ve[27];
        ve[0] = vx * inv; ve[1] = vy * inv; ve[2] = vz * inv;
        #pragma unroll
        for (int i = 0; i < 3; ++i)
            #pragma unroll
            for (int f = 0; f < 4; ++f) {
                float ang = ve[i] * (float)(1 << f);
                ve[3  + i * 4 + f] = __sinf(ang);
                ve[15 + i * 4 + f] = __cosf(ang);
            }
        unsigned vpk[14];
        #pragma unroll
        for (int p2i = 0; p2i < 13; ++p2i) vpk[p2i] = pack2(ve[2 * p2i], ve[2 * p2i + 1]);
        vpk[13] = pack2(ve[26], 1.0f);                  // ones-row at k=39

        // ---------------- feat packs + layer0 B-frags (register shuffles) -----
        unsigned flo[4], fhi[2];
        #pragma unroll
        for (int r = 0; r < 4; ++r) flo[r] = pack2(feat[2 * r], feat[2 * r + 1]);
        fhi[0] = pack2(feat[8], feat[9]);
        fhi[1] = pack2(feat[10], feat[11]);

        FragU bf[2][3];
        #pragma unroll
        for (int nt = 0; nt < 2; ++nt) {
            int src = nt * 32 + nidx;
            unsigned m0 = __shfl(flo[0], src), m1 = __shfl(flo[1], src);
            unsigned m2 = __shfl(flo[2], src), m3 = __shfl(flo[3], src);
            unsigned h0 = __shfl(fhi[0], src), h1 = __shfl(fhi[1], src);
            bf[nt][0].u[0] = qh ? h0 : m0;          // k 0-7 | 8-15 (feat + v0..3)
            bf[nt][0].u[1] = qh ? h1 : m1;
            bf[nt][0].u[2] = qh ? vpk[0] : m2;
            bf[nt][0].u[3] = qh ? vpk[1] : m3;
            bf[nt][1].u[0] = qh ? vpk[6] : vpk[2];  // k 16-31 (v4..19)
            bf[nt][1].u[1] = qh ? vpk[7] : vpk[3];
            bf[nt][1].u[2] = qh ? vpk[8] : vpk[4];
            bf[nt][1].u[3] = qh ? vpk[9] : vpk[5];
            bf[nt][2].u[0] = qh ? 0u : vpk[10];     // k 32-47 (v20..26, 1.0, zeros)
            bf[nt][2].u[1] = qh ? 0u : vpk[11];
            bf[nt][2].u[2] = qh ? 0u : vpk[12];
            bf[nt][2].u[3] = qh ? 0u : vpk[13];
        }

        // ---------------- layer0 MFMA + C->B transition (shuffle) -------------
        FragU hf0[8], hf1[8];   // layer1 B-frags, k-steps of 16, both n-tiles
        const unsigned short* w0row = &s_w0a[(nidx) * W0P + qh * 8];
        #pragma unroll
        for (int mt = 0; mt < 4; ++mt) {
            f32x16 aA = {}, aB = {};
            #pragma unroll
            for (int kk = 0; kk < 3; ++kk) {
                bf16x8 af = ld_frag(w0row + mt * 32 * W0P + kk * 16);
                aA = __builtin_amdgcn_mfma_f32_32x32x16_bf16(af, bf[0][kk].v, aA, 0, 0, 0);
                aB = __builtin_amdgcn_mfma_f32_32x32x16_bf16(af, bf[1][kk].v, aB, 0, 0, 0);
            }
            #pragma unroll
            for (int nt = 0; nt < 2; ++nt) {
                const f32x16& ac = nt ? aB : aA;
                FragU* hf = nt ? hf1 : hf0;
                unsigned p[8];
                #pragma unroll
                for (int r2 = 0; r2 < 8; ++r2)
                    p[r2] = pack2(fmaxf(ac[2 * r2], 0.f), fmaxf(ac[2 * r2 + 1], 0.f));
                unsigned g0[8], g1[8];
                #pragma unroll
                for (int r2 = 0; r2 < 8; ++r2) {
                    g0[r2] = __shfl(p[r2], nidx);
                    g1[r2] = __shfl(p[r2], nidx + 32);
                }
                hf[2 * mt + 0].u[0] = qh ? g0[2] : g0[0];
                hf[2 * mt + 0].u[1] = qh ? g0[3] : g0[1];
                hf[2 * mt + 0].u[2] = qh ? g1[2] : g1[0];
                hf[2 * mt + 0].u[3] = qh ? g1[3] : g1[1];
                hf[2 * mt + 1].u[0] = qh ? g0[6] : g0[4];
                hf[2 * mt + 1].u[1] = qh ? g0[7] : g0[5];
                hf[2 * mt + 1].u[2] = qh ? g1[6] : g1[4];
                hf[2 * mt + 1].u[3] = qh ? g1[7] : g1[5];
            }
        }

        // ---------------- layer1 MFMA + layer2 (fp32 VALU) --------------------
        float rA0 = 0.f, rA1 = 0.f, rA2 = 0.f;
        float rB0 = 0.f, rB1 = 0.f, rB2 = 0.f;
        const unsigned short* w1row = &s_w1a[(nidx) * W1P + qh * 8];
        #pragma unroll
        for (int mt2 = 0; mt2 < 4; ++mt2) {
            f32x16 cA = {}, cB = {};
            #pragma unroll
            for (int kk = 0; kk < 8; ++kk) {
                bf16x8 af = ld_frag(w1row + mt2 * 32 * W1P + kk * 16);
                cA = __builtin_amdgcn_mfma_f32_32x32x16_bf16(af, hf0[kk].v, cA, 0, 0, 0);
                cB = __builtin_amdgcn_mfma_f32_32x32x16_bf16(af, hf1[kk].v, cB, 0, 0, 0);
            }
            #pragma unroll
            for (int reg = 0; reg < 16; ++reg) {
                int dim = mt2 * 32 + (reg & 3) + 8 * (reg >> 2) + 4 * qh;
                float4 wb = s_w2b[dim];                 // {w2 row, b1}
                float hvA = fmaxf(cA[reg] + wb.w, 0.f);
                rA0 = fmaf(hvA, wb.x, rA0); rA1 = fmaf(hvA, wb.y, rA1); rA2 = fmaf(hvA, wb.z, rA2);
                float hvB = fmaxf(cB[reg] + wb.w, 0.f);
                rB0 = fmaf(hvB, wb.x, rB0); rB1 = fmaf(hvB, wb.y, rB1); rB2 = fmaf(hvB, wb.z, rB2);
            }
        }

        // pair-combine (lane l <-> l^32 hold complementary dims of same sample)
        rA0 += __shfl_xor(rA0, 32); rA1 += __shfl_xor(rA1, 32); rA2 += __shfl_xor(rA2, 32);
        rB0 += __shfl_xor(rB0, 32); rB1 += __shfl_xor(rB1, 32); rB2 += __shfl_xor(rB2, 32);

        float wgtA = __shfl(wgt, nidx);
        float wgtB = __shfl(wgt, nidx + 32);
        float cA0 = wgtA * __builtin_amdgcn_rcpf(1.f + __expf(-(rA0 + b2x)));
        float cA1 = wgtA * __builtin_amdgcn_rcpf(1.f + __expf(-(rA1 + b2y)));
        float cA2 = wgtA * __builtin_amdgcn_rcpf(1.f + __expf(-(rA2 + b2z)));
        float cB0 = wgtB * __builtin_amdgcn_rcpf(1.f + __expf(-(rB0 + b2x)));
        float cB1 = wgtB * __builtin_amdgcn_rcpf(1.f + __expf(-(rB1 + b2y)));
        float cB2 = wgtB * __builtin_amdgcn_rcpf(1.f + __expf(-(rB2 + b2z)));

        float s0 = (lane < 32) ? (cA0 + cB0) : 0.f;
        float s1 = (lane < 32) ? (cA1 + cB1) : 0.f;
        float s2 = (lane < 32) ? (cA2 + cB2) : 0.f;
        #pragma unroll
        for (int off = 32; off > 0; off >>= 1) {
            s0 += __shfl_down(s0, off);
            s1 += __shfl_down(s1, off);
            s2 += __shfl_down(s2, off);
        }
        if (lane == 0) {
            s_red[par][w][0] = s0; s_red[par][w][1] = s1; s_red[par][w][2] = s2;
        }
        __syncthreads();
        if (t == 0) {
            out[ray * 3 + 0] = s_red[par][0][0] + s_red[par][1][0] + s_red[par][2][0] + s_red[par][3][0] + ainv;
            out[ray * 3 + 1] = s_red[par][0][1] + s_red[par][1][1] + s_red[par][2][1] + s_red[par][3][1] + ainv;
            out[ray * 3 + 2] = s_red[par][0][2] + s_red[par][1][2] + s_red[par][2][2] + s_red[par][3][2] + ainv;
        }
    }
}

extern "C" void kernel_launch(void* const* d_in, const int* in_sizes, int n_in,
                              void* d_out, int out_size, void* d_ws, size_t ws_size,
                              hipStream_t stream) {
    const float* ray_pts      = (const float*)d_in[0];
    const float* viewdirs     = (const float*)d_in[1];
    const float* density_grid = (const float*)d_in[2];
    const float* k0           = (const float*)d_in[3];
    const float* w0           = (const float*)d_in[4];
    const float* b0           = (const float*)d_in[5];
    const float* w1           = (const float*)d_in[6];
    const float* b1           = (const float*)d_in[7];
    const float* w2           = (const float*)d_in[8];
    const float* b2           = (const float*)d_in[9];
    float*       outp         = (float*)d_out;

    dvgo_mfma<<<dim3(NRAYS / RPB), dim3(256), 0, stream>>>(
        ray_pts, viewdirs, density_grid, k0, w0, b0, w1, b1, w2, b2, outp);
}

// Round 3
// 597.148 us; speedup vs baseline: 4.6673x; 1.1251x over previous
//
#include <hip/hip_runtime.h>
#include <math.h>

#define NRAYS 8192
#define NSAMP 256
#define GD    160
#define NVOX  (GD*GD*GD)
#define CF    12
#define HID   128
#define RPB   16           // rays per block
#define W0P   56           // s_w0a row pitch (bf16): 112 B, stride 28 words, gcd(28,32)=4 -> 8 bank-starts
#define W1P   136          // s_w1a row pitch (bf16): 272 B, stride 68 words, gcd(68,32)=4 -> 8 bank-starts

#define WS_NEED ((size_t)NVOX * 32)   // packed voxel grid: 12 bf16 feat + fp32 dens + pad

static constexpr float ACT_SHIFT = -13.815509557963774f;
static constexpr float EPSF      = 1e-10f;

typedef __attribute__((ext_vector_type(8)))  short bf16x8;
typedef __attribute__((ext_vector_type(16))) float f32x16;

union FragU { unsigned u[4]; uint4 q; bf16x8 v; };

__device__ __forceinline__ unsigned short bf16rne(float f) {
    unsigned u = __float_as_uint(f);
    return (unsigned short)((u + 0x7FFFu + ((u >> 16) & 1u)) >> 16);
}
// pack two fp32 -> bf16x2 (truncate): low half = lo, high half = hi
__device__ __forceinline__ unsigned pack2(float lo, float hi) {
    return __builtin_amdgcn_perm(__float_as_uint(hi), __float_as_uint(lo), 0x07060302u);
}
__device__ __forceinline__ unsigned pack2rne(float lo, float hi) {
    return ((unsigned)bf16rne(hi) << 16) | (unsigned)bf16rne(lo);
}
__device__ __forceinline__ bf16x8 ld_frag(const unsigned short* p) {
    FragU f; f.q = *(const uint4*)p; return f.v;
}

// ---------------- prepack: density+k0 -> bf16 packed voxel grid --------------
__global__ __launch_bounds__(256)
void dvgo_prepack(const float* __restrict__ density_grid,
                  const float* __restrict__ k0,
                  uint4* __restrict__ pk)
{
    int v = blockIdx.x * 256 + threadIdx.x;
    if (v >= NVOX) return;
    const float4* kp = (const float4*)(k0 + (size_t)v * CF);
    float4 a = kp[0], b = kp[1], c = kp[2];
    float d = density_grid[v];
    uint4 o0, o1;
    o0.x = pack2rne(a.x, a.y); o0.y = pack2rne(a.z, a.w);
    o0.z = pack2rne(b.x, b.y); o0.w = pack2rne(b.z, b.w);
    o1.x = pack2rne(c.x, c.y); o1.y = pack2rne(c.z, c.w);
    o1.z = __float_as_uint(d); o1.w = 0u;
    pk[(size_t)v * 2 + 0] = o0;
    pk[(size_t)v * 2 + 1] = o1;
}

__device__ __forceinline__ void acc_corner(uint4 a, uint4 b, float wc,
                                           float (&feat)[CF], float& dens) {
    unsigned u[6] = {a.x, a.y, a.z, a.w, b.x, b.y};
    #pragma unroll
    for (int i = 0; i < 6; ++i) {
        float lo = __uint_as_float(u[i] << 16);
        float hi = __uint_as_float(u[i] & 0xffff0000u);
        feat[2*i]   = fmaf(lo, wc, feat[2*i]);
        feat[2*i+1] = fmaf(hi, wc, feat[2*i+1]);
    }
    dens = fmaf(__uint_as_float(b.z), wc, dens);
}

// ---------------- fused main kernel ------------------------------------------
template<bool PACKED>
__global__ __launch_bounds__(256, 3)
void dvgo_mfma(const float* __restrict__ ray_pts,
               const float* __restrict__ viewdirs,
               const float* __restrict__ density_grid,
               const float* __restrict__ k0,
               const uint4* __restrict__ pk,
               const float* __restrict__ w0,
               const float* __restrict__ b0,
               const float* __restrict__ w1,
               const float* __restrict__ b1,
               const float* __restrict__ w2,
               const float* __restrict__ b2,
               float* __restrict__ out)
{
    __shared__ __align__(16) unsigned short s_w1a[HID * W1P];  // W1^T bf16  34.8 KB
    __shared__ __align__(16) unsigned short s_w0a[HID * W0P];  // W0^T bf16  14.3 KB
    __shared__ __align__(16) float4 s_w2b[HID];                // {w2 row, b1} 2 KB
    __shared__ float s_wtot[2][4];
    __shared__ float s_red[2][4][3];

    const int t    = threadIdx.x;
    const int lane = t & 63;
    const int w    = t >> 6;
    const int nidx = lane & 31;
    const int qh   = lane >> 5;

    // ---------------- per-block weight staging (bf16, transposed) -------------
    for (int e = t; e < HID * HID; e += 256) {
        int i = e >> 7, o = e & 127;
        s_w1a[o * W1P + i] = bf16rne(w1[e]);
    }
    for (int e = t; e < 39 * HID; e += 256) {
        int i = e >> 7, o = e & 127;
        s_w0a[o * W0P + i] = bf16rne(w0[e]);
    }
    if (t < HID) {
        s_w0a[t * W0P + 39] = bf16rne(b0[t]);
        #pragma unroll
        for (int i = 40; i < 48; ++i) s_w0a[t * W0P + i] = 0;
        s_w2b[t] = make_float4(w2[t * 3 + 0], w2[t * 3 + 1], w2[t * 3 + 2], b1[t]);
    }
    const float b2x = b2[0], b2y = b2[1], b2z = b2[2];
    __syncthreads();

    #pragma unroll 1
    for (int j = 0; j < RPB; ++j) {
        const int ray = blockIdx.x * RPB + j;
        const int par = j & 1;

        // ---------------- trilinear gather, sample = t ------------------------
        float px = ray_pts[(ray * NSAMP + t) * 3 + 0];
        float py = ray_pts[(ray * NSAMP + t) * 3 + 1];
        float pz = ray_pts[(ray * NSAMP + t) * 3 + 2];
        px = fminf(fmaxf(px, 0.f), 1.f) * (float)(GD - 1);
        py = fminf(fmaxf(py, 0.f), 1.f) * (float)(GD - 1);
        pz = fminf(fmaxf(pz, 0.f), 1.f) * (float)(GD - 1);
        int ix = min((int)px, GD - 2);
        int iy = min((int)py, GD - 2);
        int iz = min((int)pz, GD - 2);
        float fx = px - (float)ix, fy = py - (float)iy, fz = pz - (float)iz;
        float wx[2] = {1.f - fx, fx}, wy[2] = {1.f - fy, fy}, wz[2] = {1.f - fz, fz};
        int base = (ix * GD + iy) * GD + iz;

        float dens = 0.f;
        float feat[CF];
        #pragma unroll
        for (int c = 0; c < CF; ++c) feat[c] = 0.f;

        if (PACKED) {
            #pragma unroll
            for (int dx = 0; dx < 2; ++dx)
            #pragma unroll
            for (int dy = 0; dy < 2; ++dy) {
                int v0 = base + dx * (GD * GD) + dy * GD;
                const uint4* p0 = pk + (size_t)v0 * 2;
                uint4 q0 = p0[0], q1 = p0[1], q2 = p0[2], q3 = p0[3];
                float wxy = wx[dx] * wy[dy];
                acc_corner(q0, q1, wxy * wz[0], feat, dens);
                acc_corner(q2, q3, wxy * wz[1], feat, dens);
            }
        } else {
            #pragma unroll
            for (int dx = 0; dx < 2; ++dx)
            #pragma unroll
            for (int dy = 0; dy < 2; ++dy)
            #pragma unroll
            for (int dz = 0; dz < 2; ++dz) {
                int idx = base + dx * (GD * GD) + dy * GD + dz;
                float wc = wx[dx] * wy[dy] * wz[dz];
                dens = fmaf(density_grid[idx], wc, dens);
                const float4* kp = (const float4*)(k0 + (long)idx * CF);
                float4 a = kp[0], b = kp[1], c = kp[2];
                feat[0]  = fmaf(a.x, wc, feat[0]);  feat[1]  = fmaf(a.y, wc, feat[1]);
                feat[2]  = fmaf(a.z, wc, feat[2]);  feat[3]  = fmaf(a.w, wc, feat[3]);
                feat[4]  = fmaf(b.x, wc, feat[4]);  feat[5]  = fmaf(b.y, wc, feat[5]);
                feat[6]  = fmaf(b.z, wc, feat[6]);  feat[7]  = fmaf(b.w, wc, feat[7]);
                feat[8]  = fmaf(c.x, wc, feat[8]);  feat[9]  = fmaf(c.y, wc, feat[9]);
                feat[10] = fmaf(c.z, wc, feat[10]); feat[11] = fmaf(c.w, wc, feat[11]);
            }
        }

        // ---------------- alpha + product scan (shfl-based) -------------------
        float sv    = dens + ACT_SHIFT;
        float rs    = rsqrtf(1.0f + __expf(sv));
        float alpha = 1.0f - rs;
        float x     = rs + EPSF;
        #pragma unroll
        for (int off = 1; off < 64; off <<= 1) {
            float y = __shfl_up(x, off);
            if (lane >= off) x *= y;
        }
        if (lane == 63) s_wtot[par][w] = x;
        __syncthreads();
        float t0 = s_wtot[par][0], t1 = s_wtot[par][1];
        float t2 = s_wtot[par][2], t3 = s_wtot[par][3];
        float pre = 1.f;
        if (w > 0) pre *= t0;
        if (w > 1) pre *= t1;
        if (w > 2) pre *= t2;
        const float ainv = t0 * t1 * t2 * t3;
        float ex = __shfl_up(x, 1);
        if (lane == 0) ex = 1.f;
        const float wgt = alpha * ex * pre;

        // ---------------- view embedding (ray-uniform) ------------------------
        float vx = viewdirs[ray * 3 + 0], vy = viewdirs[ray * 3 + 1], vz = viewdirs[ray * 3 + 2];
        float inv = 1.0f / (sqrtf(vx * vx + vy * vy + vz * vz) + EPSF);
        float ve[27];
        ve[0] = vx * inv; ve[1] = vy * inv; ve[2] = vz * inv;
        #pragma unroll
        for (int i = 0; i < 3; ++i)
            #pragma unroll
            for (int f = 0; f < 4; ++f) {
                float ang = ve[i] * (float)(1 << f);
                ve[3  + i * 4 + f] = __sinf(ang);
                ve[15 + i * 4 + f] = __cosf(ang);
            }
        unsigned vpk[14];
        #pragma unroll
        for (int p2i = 0; p2i < 13; ++p2i) vpk[p2i] = pack2(ve[2 * p2i], ve[2 * p2i + 1]);
        vpk[13] = pack2(ve[26], 1.0f);

        // ---------------- feat packs + layer0 B-frags -------------------------
        unsigned flo[4], fhi[2];
        #pragma unroll
        for (int r = 0; r < 4; ++r) flo[r] = pack2(feat[2 * r], feat[2 * r + 1]);
        fhi[0] = pack2(feat[8], feat[9]);
        fhi[1] = pack2(feat[10], feat[11]);

        FragU bf[2][3];
        #pragma unroll
        for (int nt = 0; nt < 2; ++nt) {
            int src = nt * 32 + nidx;
            unsigned m0 = __shfl(flo[0], src), m1 = __shfl(flo[1], src);
            unsigned m2 = __shfl(flo[2], src), m3 = __shfl(flo[3], src);
            unsigned h0 = __shfl(fhi[0], src), h1 = __shfl(fhi[1], src);
            bf[nt][0].u[0] = qh ? h0 : m0;
            bf[nt][0].u[1] = qh ? h1 : m1;
            bf[nt][0].u[2] = qh ? vpk[0] : m2;
            bf[nt][0].u[3] = qh ? vpk[1] : m3;
            bf[nt][1].u[0] = qh ? vpk[6] : vpk[2];
            bf[nt][1].u[1] = qh ? vpk[7] : vpk[3];
            bf[nt][1].u[2] = qh ? vpk[8] : vpk[4];
            bf[nt][1].u[3] = qh ? vpk[9] : vpk[5];
            bf[nt][2].u[0] = qh ? 0u : vpk[10];
            bf[nt][2].u[1] = qh ? 0u : vpk[11];
            bf[nt][2].u[2] = qh ? 0u : vpk[12];
            bf[nt][2].u[3] = qh ? 0u : vpk[13];
        }

        // ---------------- layer0 MFMA + C->B transition -----------------------
        FragU hf0[8], hf1[8];
        const unsigned short* w0row = &s_w0a[nidx * W0P + qh * 8];
        #pragma unroll
        for (int mt = 0; mt < 4; ++mt) {
            f32x16 aA = {}, aB = {};
            #pragma unroll
            for (int kk = 0; kk < 3; ++kk) {
                bf16x8 af = ld_frag(w0row + mt * 32 * W0P + kk * 16);
                aA = __builtin_amdgcn_mfma_f32_32x32x16_bf16(af, bf[0][kk].v, aA, 0, 0, 0);
                aB = __builtin_amdgcn_mfma_f32_32x32x16_bf16(af, bf[1][kk].v, aB, 0, 0, 0);
            }
            #pragma unroll
            for (int nt = 0; nt < 2; ++nt) {
                const f32x16& ac = nt ? aB : aA;
                FragU* hf = nt ? hf1 : hf0;
                unsigned p[8];
                #pragma unroll
                for (int r2 = 0; r2 < 8; ++r2)
                    p[r2] = pack2(fmaxf(ac[2 * r2], 0.f), fmaxf(ac[2 * r2 + 1], 0.f));
                unsigned g0[8], g1[8];
                #pragma unroll
                for (int r2 = 0; r2 < 8; ++r2) {
                    g0[r2] = __shfl(p[r2], nidx);
                    g1[r2] = __shfl(p[r2], nidx + 32);
                }
                hf[2 * mt + 0].u[0] = qh ? g0[2] : g0[0];
                hf[2 * mt + 0].u[1] = qh ? g0[3] : g0[1];
                hf[2 * mt + 0].u[2] = qh ? g1[2] : g1[0];
                hf[2 * mt + 0].u[3] = qh ? g1[3] : g1[1];
                hf[2 * mt + 1].u[0] = qh ? g0[6] : g0[4];
                hf[2 * mt + 1].u[1] = qh ? g0[7] : g0[5];
                hf[2 * mt + 1].u[2] = qh ? g1[6] : g1[4];
                hf[2 * mt + 1].u[3] = qh ? g1[7] : g1[5];
            }
        }

        // ---------------- layer1 MFMA + layer2 (fp32 VALU) --------------------
        float rA0 = 0.f, rA1 = 0.f, rA2 = 0.f;
        float rB0 = 0.f, rB1 = 0.f, rB2 = 0.f;
        const unsigned short* w1row = &s_w1a[nidx * W1P + qh * 8];
        #pragma unroll
        for (int mt2 = 0; mt2 < 4; ++mt2) {
            f32x16 cA = {}, cB = {};
            #pragma unroll
            for (int kk = 0; kk < 8; ++kk) {
                bf16x8 af = ld_frag(w1row + mt2 * 32 * W1P + kk * 16);
                cA = __builtin_amdgcn_mfma_f32_32x32x16_bf16(af, hf0[kk].v, cA, 0, 0, 0);
                cB = __builtin_amdgcn_mfma_f32_32x32x16_bf16(af, hf1[kk].v, cB, 0, 0, 0);
            }
            #pragma unroll
            for (int reg = 0; reg < 16; ++reg) {
                int dim = mt2 * 32 + (reg & 3) + 8 * (reg >> 2) + 4 * qh;
                float4 wb = s_w2b[dim];
                float hvA = fmaxf(cA[reg] + wb.w, 0.f);
                rA0 = fmaf(hvA, wb.x, rA0); rA1 = fmaf(hvA, wb.y, rA1); rA2 = fmaf(hvA, wb.z, rA2);
                float hvB = fmaxf(cB[reg] + wb.w, 0.f);
                rB0 = fmaf(hvB, wb.x, rB0); rB1 = fmaf(hvB, wb.y, rB1); rB2 = fmaf(hvB, wb.z, rB2);
            }
        }

        rA0 += __shfl_xor(rA0, 32); rA1 += __shfl_xor(rA1, 32); rA2 += __shfl_xor(rA2, 32);
        rB0 += __shfl_xor(rB0, 32); rB1 += __shfl_xor(rB1, 32); rB2 += __shfl_xor(rB2, 32);

        float wgtA = __shfl(wgt, nidx);
        float wgtB = __shfl(wgt, nidx + 32);
        float cA0 = wgtA * __builtin_amdgcn_rcpf(1.f + __expf(-(rA0 + b2x)));
        float cA1 = wgtA * __builtin_amdgcn_rcpf(1.f + __expf(-(rA1 + b2y)));
        float cA2 = wgtA * __builtin_amdgcn_rcpf(1.f + __expf(-(rA2 + b2z)));
        float cB0 = wgtB * __builtin_amdgcn_rcpf(1.f + __expf(-(rB0 + b2x)));
        float cB1 = wgtB * __builtin_amdgcn_rcpf(1.f + __expf(-(rB1 + b2y)));
        float cB2 = wgtB * __builtin_amdgcn_rcpf(1.f + __expf(-(rB2 + b2z)));

        float s0 = (lane < 32) ? (cA0 + cB0) : 0.f;
        float s1 = (lane < 32) ? (cA1 + cB1) : 0.f;
        float s2 = (lane < 32) ? (cA2 + cB2) : 0.f;
        #pragma unroll
        for (int off = 32; off > 0; off >>= 1) {
            s0 += __shfl_down(s0, off);
            s1 += __shfl_down(s1, off);
            s2 += __shfl_down(s2, off);
        }
        if (lane == 0) {
            s_red[par][w][0] = s0; s_red[par][w][1] = s1; s_red[par][w][2] = s2;
        }
        __syncthreads();
        if (t == 0) {
            out[ray * 3 + 0] = s_red[par][0][0] + s_red[par][1][0] + s_red[par][2][0] + s_red[par][3][0] + ainv;
            out[ray * 3 + 1] = s_red[par][0][1] + s_red[par][1][1] + s_red[par][2][1] + s_red[par][3][1] + ainv;
            out[ray * 3 + 2] = s_red[par][0][2] + s_red[par][1][2] + s_red[par][2][2] + s_red[par][3][2] + ainv;
        }
    }
}

extern "C" void kernel_launch(void* const* d_in, const int* in_sizes, int n_in,
                              void* d_out, int out_size, void* d_ws, size_t ws_size,
                              hipStream_t stream) {
    const float* ray_pts      = (const float*)d_in[0];
    const float* viewdirs     = (const float*)d_in[1];
    const float* density_grid = (const float*)d_in[2];
    const float* k0           = (const float*)d_in[3];
    const float* w0           = (const float*)d_in[4];
    const float* b0           = (const float*)d_in[5];
    const float* w1           = (const float*)d_in[6];
    const float* b1           = (const float*)d_in[7];
    const float* w2           = (const float*)d_in[8];
    const float* b2           = (const float*)d_in[9];
    float*       outp         = (float*)d_out;

    if (ws_size >= WS_NEED) {
        uint4* pk = (uint4*)d_ws;
        dvgo_prepack<<<dim3((NVOX + 255) / 256), dim3(256), 0, stream>>>(
            density_grid, k0, pk);
        dvgo_mfma<true><<<dim3(NRAYS / RPB), dim3(256), 0, stream>>>(
            ray_pts, viewdirs, density_grid, k0, pk, w0, b0, w1, b1, w2, b2, outp);
    } else {
        dvgo_mfma<false><<<dim3(NRAYS / RPB), dim3(256), 0, stream>>>(
            ray_pts, viewdirs, density_grid, k0, (const uint4*)d_ws,
            w0, b0, w1, b1, w2, b2, outp);
    }
}